// Round 5
// baseline (2912.102 us; speedup 1.0000x reference)
//
#include <hip/hip_runtime.h>

#define NF 8192
#define KN 48
#define TM 16

typedef __attribute__((ext_vector_type(8))) short short8;
typedef __attribute__((ext_vector_type(4))) float f32x4;

__device__ __forceinline__ unsigned short bf16e(float f) {
    return (unsigned short)((__float_as_uint(f) + 0x8000u) >> 16);
}
__device__ __forceinline__ float bf16d(unsigned hb) { return __uint_as_float(hb << 16); }

// ---------------------------------------------------------------------------
// geometry: ball->cube + trilinear corner weights for one neighbor
// packs 8 entries of (tap<<16 | bf16(weight)) into g[0..7]
// ---------------------------------------------------------------------------
__device__ __forceinline__ void pn_geom(float rx, float ry, float rz, unsigned* g)
{
    float d2  = rx * rx + ry * ry + rz * rz;
    float om  = 1.0f - d2;
    float win = om * om * om;
    win = fminf(fmaxf(win, 0.0f), 1.0f);

    float rxy2 = rx * rx + ry * ry;
    float rho  = sqrtf(rxy2 + rz * rz + 1e-8f);
    float rxyv = sqrtf(rxy2 + 1e-8f);
    bool  pole = (rxy2 <= 1.25f * rz * rz);
    float s    = pole ? sqrtf(3.0f * rho / (rho + fabsf(rz))) : (rho / rxyv);
    float cx = rx * s, cy = ry * s;
    float sgnz = (rz > 0.0f) ? 1.0f : ((rz < 0.0f) ? -1.0f : 0.0f);
    float cz   = pole ? sgnz * rho : 1.5f * rz;

    float rr   = sqrtf(cx * cx + cy * cy + 1e-8f);
    bool  cond = fabsf(cx) >= fabsf(cy);
    float sx = (cx >= 0.0f) ? 1.0f : -1.0f;
    float sy = (cy >= 0.0f) ? 1.0f : -1.0f;
    float safecx = (fabsf(cx) > 1e-8f) ? cx : 1.0f;
    float safecy = (fabsf(cy) > 1e-8f) ? cy : 1.0f;
    const float C4PI = 1.2732395447351628f;
    float u = cond ? (sx * rr) : (sy * C4PI * rr * atanf(cx / safecy));
    float v = cond ? (sx * C4PI * rr * atanf(cy / safecx)) : (sy * rr);
    if (rho < 1e-6f) { u = 0.0f; v = 0.0f; cz = 0.0f; }

    float tx = fminf(fmaxf((u  * 0.5f + 0.5f) * 3.0f, 0.0f), 3.0f);
    float ty = fminf(fmaxf((v  * 0.5f + 0.5f) * 3.0f, 0.0f), 3.0f);
    float tz = fminf(fmaxf((cz * 0.5f + 0.5f) * 3.0f, 0.0f), 3.0f);
    int ix = (int)floorf(tx); ix = ix < 0 ? 0 : (ix > 2 ? 2 : ix);
    int iy = (int)floorf(ty); iy = iy < 0 ? 0 : (iy > 2 ? 2 : iy);
    int iz = (int)floorf(tz); iz = iz < 0 ? 0 : (iz > 2 ? 2 : iz);
    float fx = tx - (float)ix, fy = ty - (float)iy, fz = tz - (float)iz;
    float wx0 = 1.0f - fx, wy0 = 1.0f - fy, wz0 = 1.0f - fz;

#pragma unroll
    for (int dx = 0; dx < 2; ++dx)
#pragma unroll
        for (int dy = 0; dy < 2; ++dy)
#pragma unroll
            for (int dz = 0; dz < 2; ++dz) {
                float w = (dx ? fx : wx0) * (dy ? fy : wy0) * (dz ? fz : wz0) * win;
                int tap = ((ix + dx) << 4) + ((iy + dy) << 2) + (iz + dz);
                g[(dx << 2) | (dy << 1) | dz] = ((unsigned)tap << 16) | (unsigned)bf16e(w);
            }
}

// ---------------------------------------------------------------------------
// prep: vel_new/pos_new, fluid feats, neighbor count, dense d0 branch
// ---------------------------------------------------------------------------
__global__ void __launch_bounds__(256) pn_prep(
    const float* __restrict__ pos, const float* __restrict__ vel,
    const int* __restrict__ nbrf,
    const float* __restrict__ d0w, const float* __restrict__ d0b,
    float* __restrict__ pos_new, float* __restrict__ feats0,
    float* __restrict__ X, float* __restrict__ nfn)
{
    int t = blockIdx.x * 256 + threadIdx.x;
    if (t >= NF) return;
    float vx = vel[t * 3 + 0], vy = vel[t * 3 + 1], vz = vel[t * 3 + 2];
    float vnx = vx, vny = vy - 9.81f * 0.02f, vnz = vz;
    float pnx = pos[t * 3 + 0] + (vx + vnx) * 0.01f;
    float pny = pos[t * 3 + 1] + (vy + vny) * 0.01f;
    float pnz = pos[t * 3 + 2] + (vz + vnz) * 0.01f;
    pos_new[t * 3 + 0] = pnx; pos_new[t * 3 + 1] = pny; pos_new[t * 3 + 2] = pnz;
    feats0[t * 4 + 0] = 1.0f; feats0[t * 4 + 1] = vnx;
    feats0[t * 4 + 2] = vny;  feats0[t * 4 + 3] = vnz;
    int cnt = 0;
    for (int k = 0; k < KN; ++k) cnt += (nbrf[t * KN + k] >= 0) ? 1 : 0;
    nfn[t] = (float)cnt;
    for (int j = 0; j < 32; ++j) {
        float s = d0b[j] + d0w[0 * 32 + j] + vnx * d0w[1 * 32 + j]
                + vny * d0w[2 * 32 + j] + vnz * d0w[3 * 32 + j];
        X[t * 96 + 64 + j] = s;
    }
}

// ---------------------------------------------------------------------------
// pack filter transposed bf16: FT[d][ch][t][c]  (d-major, K contiguous)
// t==64 row = dense weights when HAS_SELF; rows/chans beyond real = 0.
// ---------------------------------------------------------------------------
template <int CIN, int COUT, int CHUNK, int ROWS_P, int HAS_SELF>
__global__ void __launch_bounds__(256) pn_pack(
    const float* __restrict__ cw, const float* __restrict__ dw,
    const float* __restrict__ cb, const float* __restrict__ db,
    unsigned short* __restrict__ FT, float* __restrict__ B)
{
    constexpr int NCH  = (CIN + CHUNK - 1) / CHUNK;
    constexpr int AK   = ROWS_P * CHUNK;
    constexpr int KTOT = NCH * AK;
    constexpr int DPAD = ((COUT + 15) / 16) * 16;
    int i = blockIdx.x * 256 + threadIdx.x;
    if (i < DPAD * KTOT) {
        int d  = i / KTOT;
        int r  = i - d * KTOT;
        int ch = r / AK; r -= ch * AK;
        int t  = r / CHUNK;
        int c  = r - t * CHUNK;
        int cin = ch * CHUNK + c;
        float v = 0.0f;
        if (d < COUT && cin < CIN) {
            if (t < 64)                    v = cw[((size_t)t * CIN + cin) * COUT + d];
            else if (HAS_SELF && t == 64)  v = dw[(size_t)cin * COUT + d];
        }
        FT[i] = bf16e(v);
    }
    if (i < COUT) B[i] = cb[i] + (HAS_SELF ? db[i] : 0.0f);
}

// ---------------------------------------------------------------------------
// fused CConv: flat corner-list scatter (fire-and-forget ds_add) + MFMA GEMM
// OUT_MODE: 0 = X-slice, 1 = plain [NF][COUT], 2 = +resid, 3 = final pos/vel
// ---------------------------------------------------------------------------
template <int CIN, int COUT, int CHUNK, int ROWS_P, int HAS_SELF, int RELU_IN, int OUT_MODE>
__global__ void __launch_bounds__(512, 4) pn_cconv(
    const float* __restrict__ qpos, const float* __restrict__ ppos,
    const float* __restrict__ feats, const int* __restrict__ nbr,
    const unsigned short* __restrict__ F2t, const float* __restrict__ bias,
    const float* __restrict__ resid, float* __restrict__ outp,
    const float* __restrict__ pos0, int out_stride, int out_off)
{
    constexpr int NCH    = (CIN + CHUNK - 1) / CHUNK;
    constexpr int AK     = ROWS_P * CHUNK;        // K per chunk (multiple of 32)
    constexpr int AKP    = AK + 8;                // padded bf16 LDS stride
    constexpr int KTOT   = NCH * AK;
    constexpr int S      = AK / 32;               // K-steps per chunk
    constexpr int DPAD   = ((COUT + 15) / 16) * 16;
    constexpr int NT     = DPAD / 16;             // d-tiles
    constexpr int SPLITK = 8 / NT;
    constexpr int SPC    = (S + SPLITK - 1) / SPLITK;
    constexpr int NGRP   = 512 / CHUNK;
    constexpr int SUBS   = NGRP / TM;             // entry-range splits per point
    constexpr int NW     = TM * AK / 2;           // packed u32 words for A
    constexpr int NR     = (NW + 511) / 512;
    constexpr int ABYTES = TM * AK * 4;
    constexpr int BIGSZ  = (ABYTES > 8192 ? ABYTES : 8192);

    static_assert(AK % 32 == 0, "AK must be multiple of 32");

    __shared__ int      sI[TM * KN];
    __shared__ int      sKN[TM];
    __shared__ unsigned sG[TM * KN * 8];                     // corner entries, pos = k*8+j
    __shared__ unsigned short sF[TM * KN * CHUNK];           // staged neighbor feats (bf16)
    __shared__ __align__(16) char sBig[BIGSZ];               // fp32 A / bf16 A / epilogue

    float*          sA32 = (float*)sBig;
    unsigned short* sAb  = (unsigned short*)sBig;
    unsigned*       sAbw = (unsigned*)sBig;
    float*          sEpi = (float*)sBig;

    const int tid  = threadIdx.x;
    const int w    = tid >> 6;
    const int lane = tid & 63;
    const int pt0  = blockIdx.x * TM;

    if (tid < TM) sKN[tid] = KN;
    __syncthreads();

    // phase 0: geometry -> corner entries at deterministic positions
    for (int e = tid; e < TM * KN; e += 512) {
        int lp = e / KN, k = e - lp * KN;
        int q  = pt0 + lp;
        int id = nbr[q * KN + k];
        if (id >= 0) {
            sI[e] = id;
            float rx = (ppos[id * 3 + 0] - qpos[q * 3 + 0]) * (1.0f / 0.1125f);
            float ry = (ppos[id * 3 + 1] - qpos[q * 3 + 1]) * (1.0f / 0.1125f);
            float rz = (ppos[id * 3 + 2] - qpos[q * 3 + 2]) * (1.0f / 0.1125f);
            unsigned g[8];
            pn_geom(rx, ry, rz, g);
#pragma unroll
            for (int j = 0; j < 8; ++j) sG[e * 8 + j] = g[j];
        } else {
            atomicMin(&sKN[lp], k);
        }
    }

    f32x4 acc = {0.0f, 0.0f, 0.0f, 0.0f};
    __syncthreads();

    for (int ch = 0; ch < NCH; ++ch) {
        const int cb0 = ch * CHUNK;

        // zero fp32 A + stage neighbor feature chunk to bf16 LDS
        {
            f32x4 z = {0.0f, 0.0f, 0.0f, 0.0f};
            for (int i = tid; i < TM * AK / 4; i += 512) ((f32x4*)sA32)[i] = z;
        }
        for (int e = tid; e < TM * KN; e += 512) {
            int lp = e / KN, k = e - lp * KN;
            if (k < sKN[lp]) {
                int id = sI[e];
                unsigned short* dst = sF + e * CHUNK;
                if constexpr (CHUNK == 8) {
                    const float4* s4 = (const float4*)(feats + (size_t)id * CIN + cb0);
                    float4 f0 = s4[0], f1 = s4[1];
                    if (RELU_IN) {
                        f0.x=fmaxf(f0.x,0.f); f0.y=fmaxf(f0.y,0.f); f0.z=fmaxf(f0.z,0.f); f0.w=fmaxf(f0.w,0.f);
                        f1.x=fmaxf(f1.x,0.f); f1.y=fmaxf(f1.y,0.f); f1.z=fmaxf(f1.z,0.f); f1.w=fmaxf(f1.w,0.f);
                    }
                    uint4 p;
                    p.x = (unsigned)bf16e(f0.x) | ((unsigned)bf16e(f0.y) << 16);
                    p.y = (unsigned)bf16e(f0.z) | ((unsigned)bf16e(f0.w) << 16);
                    p.z = (unsigned)bf16e(f1.x) | ((unsigned)bf16e(f1.y) << 16);
                    p.w = (unsigned)bf16e(f1.z) | ((unsigned)bf16e(f1.w) << 16);
                    *((uint4*)dst) = p;
                } else if constexpr (CIN >= 4) {    // CHUNK == 4, CIN == 4
                    float4 f = *(const float4*)(feats + (size_t)id * CIN + cb0);
                    if (RELU_IN) { f.x=fmaxf(f.x,0.f); f.y=fmaxf(f.y,0.f); f.z=fmaxf(f.z,0.f); f.w=fmaxf(f.w,0.f); }
                    uint2 p;
                    p.x = (unsigned)bf16e(f.x) | ((unsigned)bf16e(f.y) << 16);
                    p.y = (unsigned)bf16e(f.z) | ((unsigned)bf16e(f.w) << 16);
                    *((uint2*)dst) = p;
                } else {                             // CHUNK == 4, CIN == 3
                    float f0 = feats[(size_t)id * 3 + 0];
                    float f1 = feats[(size_t)id * 3 + 1];
                    float f2 = feats[(size_t)id * 3 + 2];
                    uint2 p;
                    p.x = (unsigned)bf16e(f0) | ((unsigned)bf16e(f1) << 16);
                    p.y = (unsigned)bf16e(f2);
                    *((uint2*)dst) = p;
                }
            }
        }
        __syncthreads();

        // scatter A-build: balanced flat ranges, one fire-and-forget ds_add/entry
        {
            const int grp = tid / CHUNK;
            const int c   = tid - grp * CHUNK;
            const int lp  = grp / SUBS;
            const int sub = grp - lp * SUBS;
            const int n8  = sKN[lp] * 8;
            const int EPG = (n8 + SUBS - 1) / SUBS;
            int e  = sub * EPG;
            const int e1 = min(n8, e + EPG);
            const unsigned* eg = sG + lp * (KN * 8);
            const unsigned short* fb = sF + lp * KN * CHUNK + c;
            float* ab = sA32 + lp * ROWS_P * CHUNK + c;
#pragma unroll 4
            for (; e < e1; ++e) {
                unsigned u = eg[e];
                float f = bf16d((unsigned)fb[(e >> 3) * CHUNK]);
                atomicAdd(ab + (int)(u >> 16) * CHUNK, bf16d(u & 0xffffu) * f);
            }
        }
        // self row (tap 64) = own feats, no scatter needed
        if constexpr (HAS_SELF) {
            if (tid < TM * CHUNK) {
                int lp2 = tid / CHUNK, c2 = tid - lp2 * CHUNK;
                float f = feats[(size_t)(pt0 + lp2) * CIN + cb0 + c2];
                if (RELU_IN) f = fmaxf(f, 0.0f);
                sA32[(lp2 * ROWS_P + 64) * CHUNK + c2] = f;
            }
        }
        __syncthreads();

        // convert fp32 A -> packed bf16 (aliased region, two-pass)
        unsigned tmp[NR];
#pragma unroll
        for (int i = 0; i < NR; ++i) {
            int idx = tid + i * 512;
            if (idx < NW) {
                int pt = idx / (AK / 2);
                int kw = idx - pt * (AK / 2);
                float f0 = sA32[pt * AK + kw * 2];
                float f1 = sA32[pt * AK + kw * 2 + 1];
                tmp[i] = (unsigned)bf16e(f0) | ((unsigned)bf16e(f1) << 16);
            }
        }
        __syncthreads();
#pragma unroll
        for (int i = 0; i < NR; ++i) {
            int idx = tid + i * 512;
            if (idx < NW) {
                int pt = idx / (AK / 2);
                int kw = idx - pt * (AK / 2);
                sAbw[pt * (AKP / 2) + kw] = tmp[i];
            }
        }
        __syncthreads();

        // MFMA tap-GEMM: out[16 pts][DPAD] += A[16][AK] * F[AK][DPAD]
        {
            const int dt = w % NT, kh = w / NT;
            const int n  = lane & 15, kg = lane >> 4;
            const int drow = dt * 16 + n;
            const unsigned short* gB = F2t + (size_t)drow * KTOT + ch * AK;
            const int s0 = kh * SPC;
            const int s1 = min(S, s0 + SPC);
            for (int s = s0; s < s1; ++s) {
                int kidx = s * 32 + kg * 8;
                short8 av = *(const short8*)(sAb + (lane & 15) * AKP + kidx);
                short8 bv = *(const short8*)(gB + kidx);
                acc = __builtin_amdgcn_mfma_f32_16x16x32_bf16(av, bv, acc, 0, 0, 0);
            }
        }
        __syncthreads();   // protect sBig/sF before next chunk rewrites
    }

    // epilogue: split-K combine + bias + output modes (sEpi aliases sBig)
#pragma unroll
    for (int r = 0; r < 4; ++r) sEpi[(w * 64 + lane) * 4 + r] = acc[r];
    __syncthreads();

    if (w < NT) {
        float sum[4];
#pragma unroll
        for (int r = 0; r < 4; ++r) {
            float s = 0.0f;
#pragma unroll
            for (int kh = 0; kh < SPLITK; ++kh)
                s += sEpi[((kh * NT + w) * 64 + lane) * 4 + r];
            sum[r] = s;
        }
        int d = w * 16 + (lane & 15);
        if (d < COUT) {
            float b = bias[d];
#pragma unroll
            for (int r = 0; r < 4; ++r) {
                int pt = (lane >> 4) * 4 + r;
                int q  = pt0 + pt;
                float y = sum[r] + b;
                if constexpr (OUT_MODE == 0) {
                    outp[q * out_stride + out_off + d] = y;
                } else if constexpr (OUT_MODE == 1) {
                    outp[q * COUT + d] = y;
                } else if constexpr (OUT_MODE == 2) {
                    outp[q * COUT + d] = y + resid[q * COUT + d];
                } else {
                    float corr = y * (1.0f / 128.0f);
                    float pn   = qpos[q * 3 + d];
                    float pc   = pn + corr;
                    outp[q * 3 + d]          = pc;
                    outp[NF * 3 + q * 3 + d] = (pc - pos0[q * 3 + d]) * (1.0f / 0.02f);
                }
            }
        }
    }
}

// ---------------------------------------------------------------------------
// host launcher
// ---------------------------------------------------------------------------
extern "C" void kernel_launch(void* const* d_in, const int* in_sizes, int n_in,
                              void* d_out, int out_size, void* d_ws, size_t ws_size,
                              hipStream_t stream)
{
    (void)in_sizes; (void)n_in; (void)out_size; (void)ws_size;

    const float* pos       = (const float*)d_in[0];
    const float* vel       = (const float*)d_in[1];
    const float* box       = (const float*)d_in[2];
    const float* box_feats = (const float*)d_in[3];
    const int*   nbrf      = (const int*)d_in[4];
    const int*   nbrb      = (const int*)d_in[5];
    const float* cf0_w = (const float*)d_in[6];
    const float* cf0_b = (const float*)d_in[7];
    const float* co0_w = (const float*)d_in[8];
    const float* co0_b = (const float*)d_in[9];
    const float* d0_w  = (const float*)d_in[10];
    const float* d0_b  = (const float*)d_in[11];
    const float* c1_w  = (const float*)d_in[12];
    const float* c1_b  = (const float*)d_in[13];
    const float* d1_w  = (const float*)d_in[14];
    const float* d1_b  = (const float*)d_in[15];
    const float* c2_w  = (const float*)d_in[16];
    const float* c2_b  = (const float*)d_in[17];
    const float* d2_w  = (const float*)d_in[18];
    const float* d2_b  = (const float*)d_in[19];
    const float* c3_w  = (const float*)d_in[20];
    const float* c3_b  = (const float*)d_in[21];
    const float* d3_w  = (const float*)d_in[22];
    const float* d3_b  = (const float*)d_in[23];

    char* ws = (char*)d_ws;
    float*          POSNEW = (float*)(ws + 0);        // 98304
    float*          FEATS0 = (float*)(ws + 98304);    // 131072
    float*          X      = (float*)(ws + 229376);   // 8192*96*4 = 3145728
    float*          X1     = (float*)(ws + 3375104);  // 2097152
    float*          X2     = (float*)(ws + 5472256);  // 2097152
    unsigned short* FT1    = (unsigned short*)(ws + 7569408); // 64*6528*2 = 835584
    unsigned short* FT2    = (unsigned short*)(ws + 8404992); // 64*4352*2 = 557056
    unsigned short* FT3    = (unsigned short*)(ws + 8962048); // 16*4352*2 = 139264
    unsigned short* FTf0   = (unsigned short*)(ws + 9101312); // 32*288*2  = 18432
    unsigned short* FTo0   = (unsigned short*)(ws + 9119744); // 32*288*2  = 18432
    float*          B1     = (float*)(ws + 9138176);
    float*          B2     = (float*)(ws + 9138432);
    float*          B3     = (float*)(ws + 9138688);
    float*          Bf0    = (float*)(ws + 9138944);
    float*          Bo0    = (float*)(ws + 9139200);

    float* out_f = (float*)d_out;

    // packs: <CIN, COUT, CHUNK, ROWS_P, HAS_SELF>
    pn_pack<96, 64, 8, 68, 1><<<(64 * 6528 + 255) / 256, 256, 0, stream>>>(c1_w, d1_w, c1_b, d1_b, FT1, B1);
    pn_pack<64, 64, 8, 68, 1><<<(64 * 4352 + 255) / 256, 256, 0, stream>>>(c2_w, d2_w, c2_b, d2_b, FT2, B2);
    pn_pack<64, 3, 8, 68, 1><<<(16 * 4352 + 255) / 256, 256, 0, stream>>>(c3_w, d3_w, c3_b, d3_b, FT3, B3);
    pn_pack<4, 32, 4, 72, 0><<<(32 * 288 + 255) / 256, 256, 0, stream>>>(cf0_w, nullptr, cf0_b, nullptr, FTf0, Bf0);
    pn_pack<3, 32, 4, 72, 0><<<(32 * 288 + 255) / 256, 256, 0, stream>>>(co0_w, nullptr, co0_b, nullptr, FTo0, Bo0);

    pn_prep<<<(NF + 255) / 256, 256, 0, stream>>>(pos, vel, nbrf, d0_w, d0_b,
                                                  POSNEW, FEATS0, X, out_f + NF * 6);

    // convs: <CIN, COUT, CHUNK, ROWS_P, HAS_SELF, RELU_IN, OUT_MODE>, grid NF/16, 512 thr
    pn_cconv<4, 32, 4, 72, 0, 0, 0><<<NF / TM, 512, 0, stream>>>(
        POSNEW, POSNEW, FEATS0, nbrf, FTf0, Bf0, nullptr, X, nullptr, 96, 32);
    pn_cconv<3, 32, 4, 72, 0, 0, 0><<<NF / TM, 512, 0, stream>>>(
        POSNEW, box, box_feats, nbrb, FTo0, Bo0, nullptr, X, nullptr, 96, 0);
    pn_cconv<96, 64, 8, 68, 1, 1, 1><<<NF / TM, 512, 0, stream>>>(
        POSNEW, POSNEW, X, nbrf, FT1, B1, nullptr, X1, nullptr, 0, 0);
    pn_cconv<64, 64, 8, 68, 1, 1, 2><<<NF / TM, 512, 0, stream>>>(
        POSNEW, POSNEW, X1, nbrf, FT2, B2, X1, X2, nullptr, 0, 0);
    pn_cconv<64, 3, 8, 68, 1, 1, 3><<<NF / TM, 512, 0, stream>>>(
        POSNEW, POSNEW, X2, nbrf, FT3, B3, nullptr, out_f, pos, 0, 0);
}

// Round 7
// 524.904 us; speedup vs baseline: 5.5479x; 5.5479x over previous
//
#include <hip/hip_runtime.h>

#define NF 8192
#define KN 48
#define TM 16

typedef __attribute__((ext_vector_type(8))) short short8;
typedef __attribute__((ext_vector_type(4))) float f32x4;

__device__ __forceinline__ unsigned short bf16e(float f) {
    return (unsigned short)((__float_as_uint(f) + 0x8000u) >> 16);
}

// ---------------------------------------------------------------------------
// geometry: ball->cube + trilinear corner weights for one neighbor
// packs 8 entries of (tap<<16 | bf16(weight)) into g[0..7]
// ---------------------------------------------------------------------------
__device__ __forceinline__ void pn_geom(float rx, float ry, float rz, unsigned* g)
{
    float d2  = rx * rx + ry * ry + rz * rz;
    float om  = 1.0f - d2;
    float win = om * om * om;
    win = fminf(fmaxf(win, 0.0f), 1.0f);

    float rxy2 = rx * rx + ry * ry;
    float rho  = sqrtf(rxy2 + rz * rz + 1e-8f);
    float rxyv = sqrtf(rxy2 + 1e-8f);
    bool  pole = (rxy2 <= 1.25f * rz * rz);
    float s    = pole ? sqrtf(3.0f * rho / (rho + fabsf(rz))) : (rho / rxyv);
    float cx = rx * s, cy = ry * s;
    float sgnz = (rz > 0.0f) ? 1.0f : ((rz < 0.0f) ? -1.0f : 0.0f);
    float cz   = pole ? sgnz * rho : 1.5f * rz;

    float rr   = sqrtf(cx * cx + cy * cy + 1e-8f);
    bool  cond = fabsf(cx) >= fabsf(cy);
    float sx = (cx >= 0.0f) ? 1.0f : -1.0f;
    float sy = (cy >= 0.0f) ? 1.0f : -1.0f;
    float safecx = (fabsf(cx) > 1e-8f) ? cx : 1.0f;
    float safecy = (fabsf(cy) > 1e-8f) ? cy : 1.0f;
    const float C4PI = 1.2732395447351628f;
    float u = cond ? (sx * rr) : (sy * C4PI * rr * atanf(cx / safecy));
    float v = cond ? (sx * C4PI * rr * atanf(cy / safecx)) : (sy * rr);
    if (rho < 1e-6f) { u = 0.0f; v = 0.0f; cz = 0.0f; }

    float tx = fminf(fmaxf((u  * 0.5f + 0.5f) * 3.0f, 0.0f), 3.0f);
    float ty = fminf(fmaxf((v  * 0.5f + 0.5f) * 3.0f, 0.0f), 3.0f);
    float tz = fminf(fmaxf((cz * 0.5f + 0.5f) * 3.0f, 0.0f), 3.0f);
    int ix = (int)floorf(tx); ix = ix < 0 ? 0 : (ix > 2 ? 2 : ix);
    int iy = (int)floorf(ty); iy = iy < 0 ? 0 : (iy > 2 ? 2 : iy);
    int iz = (int)floorf(tz); iz = iz < 0 ? 0 : (iz > 2 ? 2 : iz);
    float fx = tx - (float)ix, fy = ty - (float)iy, fz = tz - (float)iz;
    float wx0 = 1.0f - fx, wy0 = 1.0f - fy, wz0 = 1.0f - fz;

#pragma unroll
    for (int dx = 0; dx < 2; ++dx)
#pragma unroll
        for (int dy = 0; dy < 2; ++dy)
#pragma unroll
            for (int dz = 0; dz < 2; ++dz) {
                float w = (dx ? fx : wx0) * (dy ? fy : wy0) * (dz ? fz : wz0) * win;
                int tap = ((ix + dx) << 4) + ((iy + dy) << 2) + (iz + dz);
                g[(dx << 2) | (dy << 1) | dz] = ((unsigned)tap << 16) | (unsigned)bf16e(w);
            }
}

// ---------------------------------------------------------------------------
// prep: vel_new/pos_new, fluid feats, neighbor count, dense d0 branch
// ---------------------------------------------------------------------------
__global__ void __launch_bounds__(256) pn_prep(
    const float* __restrict__ pos, const float* __restrict__ vel,
    const int* __restrict__ nbrf,
    const float* __restrict__ d0w, const float* __restrict__ d0b,
    float* __restrict__ pos_new, float* __restrict__ feats0,
    float* __restrict__ X, float* __restrict__ nfn)
{
    int t = blockIdx.x * 256 + threadIdx.x;
    if (t >= NF) return;
    float vx = vel[t * 3 + 0], vy = vel[t * 3 + 1], vz = vel[t * 3 + 2];
    float vnx = vx, vny = vy - 9.81f * 0.02f, vnz = vz;
    float pnx = pos[t * 3 + 0] + (vx + vnx) * 0.01f;
    float pny = pos[t * 3 + 1] + (vy + vny) * 0.01f;
    float pnz = pos[t * 3 + 2] + (vz + vnz) * 0.01f;
    pos_new[t * 3 + 0] = pnx; pos_new[t * 3 + 1] = pny; pos_new[t * 3 + 2] = pnz;
    feats0[t * 4 + 0] = 1.0f; feats0[t * 4 + 1] = vnx;
    feats0[t * 4 + 2] = vny;  feats0[t * 4 + 3] = vnz;
    int cnt = 0;
    for (int k = 0; k < KN; ++k) cnt += (nbrf[t * KN + k] >= 0) ? 1 : 0;
    nfn[t] = (float)cnt;
    for (int j = 0; j < 32; ++j) {
        float s = d0b[j] + d0w[0 * 32 + j] + vnx * d0w[1 * 32 + j]
                + vny * d0w[2 * 32 + j] + vnz * d0w[3 * 32 + j];
        X[t * 96 + 64 + j] = s;
    }
}

// ---------------------------------------------------------------------------
// pack:  F2t[mt][cc][dt][dd 16][k2=tl*16+cl : 256]  (B^T, K contiguous, bf16)
//        FD[d][CINP] (dense branch, B^T), B = cb (+db)
// ---------------------------------------------------------------------------
template <int CIN, int COUT, int HAS_SELF>
__global__ void __launch_bounds__(256) pn_pack(
    const float* __restrict__ cw, const float* __restrict__ dw,
    const float* __restrict__ cb, const float* __restrict__ db,
    unsigned short* __restrict__ F2t, unsigned short* __restrict__ FD,
    float* __restrict__ B)
{
    constexpr int CINP = ((CIN + 15) / 16) * 16;
    constexpr int NCC  = CINP / 16;
    constexpr int DPAD = ((COUT + 15) / 16) * 16;
    constexpr int NT   = DPAD / 16;
    const int total1 = 4 * NCC * NT * 16 * 256;
    const int total2 = HAS_SELF ? DPAD * CINP : 0;
    int i = blockIdx.x * 256 + threadIdx.x;
    if (i < total1) {
        int k2 = i & 255;
        int q  = i >> 8;
        int dd = q & 15; q >>= 4;
        int dt = q % NT; q /= NT;
        int cc = q % NCC;
        int mt = q / NCC;
        int t   = mt * 16 + (k2 >> 4);
        int cin = cc * 16 + (k2 & 15);
        int d   = dt * 16 + dd;
        float v = 0.0f;
        if (cin < CIN && d < COUT) v = cw[((size_t)t * CIN + cin) * COUT + d];
        F2t[i] = bf16e(v);
    } else if (i < total1 + total2) {
        int j = i - total1;
        int d = j / CINP, c = j % CINP;
        float v = 0.0f;
        if (c < CIN && d < COUT) v = dw[(size_t)c * COUT + d];
        FD[j] = bf16e(v);
    }
    if (i < COUT) B[i] = cb[i] + (HAS_SELF ? db[i] : 0.0f);
}

// ---------------------------------------------------------------------------
// fused CConv, all-MFMA:
//   phase0: geometry -> corner entries sG (sentinel 0xFFFF0000 for invalid)
//   per tap-tile mt: build dense W_mt[pt][16 taps][48 k] (write-once, no atomics)
//     per c-chunk cc: stage featsT -> step1 MFMA (A=W,B=featsT) -> A2 bf16
//                     step2 MFMA (A=A2 pts x k2, B=F2t) -> acc  [guarded split-K]
//   self/dense branch: A3 = relu(self feats) MFMA with FD
// OUT_MODE: 0 = X-slice, 1 = plain, 2 = +resid, 3 = final pos/vel
// ---------------------------------------------------------------------------
template <int CIN, int COUT, int HAS_SELF, int RELU_IN, int OUT_MODE>
__global__ void __launch_bounds__(512, 1) pn_cconv(
    const float* __restrict__ qpos, const float* __restrict__ ppos,
    const float* __restrict__ feats, const int* __restrict__ nbr,
    const unsigned short* __restrict__ F2t, const unsigned short* __restrict__ FD,
    const float* __restrict__ bias,
    const float* __restrict__ resid, float* __restrict__ outp,
    const float* __restrict__ pos0, int out_stride, int out_off)
{
    constexpr int CINP   = ((CIN + 15) / 16) * 16;
    constexpr int NCC    = CINP / 16;
    constexpr int DPAD   = ((COUT + 15) / 16) * 16;
    constexpr int NT     = DPAD / 16;
    constexpr int SPLITK = 8 / NT;
    constexpr int S2     = 8;                       // 32-wide K-steps per (mt,cc): 256/32
    constexpr int SPC    = (S2 + SPLITK - 1) / SPLITK;
    constexpr int WST    = 56;    // W/featsT row stride (bf16 elems, 112B, 16B-aligned)
    constexpr int A2ST   = 264;   // A2 row stride

    __shared__ int      sI[TM * KN];
    __shared__ int      sKN[TM];
    __shared__ __align__(16) unsigned sG[TM * KN * 8];            // 24KB
    __shared__ __align__(16) unsigned short sW [TM * 16 * WST];   // 28KB [pt][tap_l][k]
    __shared__ __align__(16) unsigned short sFT[TM * 16 * WST];   // 28KB [pt][c_l][k]
    __shared__ __align__(16) unsigned short sA2[TM * A2ST];       // 8.25KB [pt][k2]
    __shared__ __align__(16) unsigned short sA3[TM * 40];         // [pt][c]
    __shared__ float    sEpi[8 * 64 * 4];                          // 8KB

    const int tid  = threadIdx.x;
    const int w    = tid >> 6;
    const int lane = tid & 63;
    const int n16  = lane & 15;
    const int kg   = lane >> 4;
    const int pt0  = blockIdx.x * TM;
    const int dt   = w % NT;
    const int kh   = w / NT;

    if (tid < TM) sKN[tid] = KN;
    __syncthreads();

    // phase 0: geometry (once per dispatch)
    for (int e = tid; e < TM * KN; e += 512) {
        int lp = e / KN, k = e - lp * KN;
        int q  = pt0 + lp;
        int id = nbr[q * KN + k];
        if (id >= 0) {
            sI[e] = id;
            float rx = (ppos[id * 3 + 0] - qpos[q * 3 + 0]) * (1.0f / 0.1125f);
            float ry = (ppos[id * 3 + 1] - qpos[q * 3 + 1]) * (1.0f / 0.1125f);
            float rz = (ppos[id * 3 + 2] - qpos[q * 3 + 2]) * (1.0f / 0.1125f);
            unsigned g[8];
            pn_geom(rx, ry, rz, g);
#pragma unroll
            for (int j = 0; j < 8; ++j) sG[e * 8 + j] = g[j];
        } else {
            atomicMin(&sKN[lp], k);
#pragma unroll
            for (int j = 0; j < 8; ++j) sG[e * 8 + j] = 0xFFFF0000u;
        }
    }

    f32x4 acc = {0.0f, 0.0f, 0.0f, 0.0f};
    __syncthreads();

    for (int mt = 0; mt < 4; ++mt) {
        const int lo = mt * 16;

        // zero + build W_mt (write-once scatter, no atomics)
        {
            uint4 z4 = make_uint4(0, 0, 0, 0);
            for (int i = tid; i < TM * 16 * WST / 8; i += 512) ((uint4*)sW)[i] = z4;
        }
        __syncthreads();
        for (int e = tid; e < TM * KN; e += 512) {
            int pt = e / KN, k = e - pt * KN;
            uint4 u0 = ((const uint4*)sG)[e * 2];
            uint4 u1 = ((const uint4*)sG)[e * 2 + 1];
            unsigned us_[8] = {u0.x, u0.y, u0.z, u0.w, u1.x, u1.y, u1.z, u1.w};
#pragma unroll
            for (int j = 0; j < 8; ++j) {
                unsigned tapf = us_[j] >> 16;
                if (tapf >= (unsigned)lo && tapf < (unsigned)(lo + 16))
                    sW[(pt * 16 + (int)(tapf - lo)) * WST + k] = (unsigned short)(us_[j] & 0xffffu);
            }
        }
        __syncthreads();

        for (int cc = 0; cc < NCC; ++cc) {
            const int cb0 = cc * 16;

            // stage transposed features: sFT[pt][c][k] (zeros for invalid k / c>=CIN)
            for (int e = tid; e < TM * KN; e += 512) {
                int pt = e / KN, k = e - pt * KN;
                unsigned short vals[16];
                if (k < sKN[pt]) {
                    int id = sI[e];
                    if constexpr (CIN % 16 == 0) {
                        const float4* s4 = (const float4*)(feats + (size_t)id * CIN + cb0);
#pragma unroll
                        for (int v4 = 0; v4 < 4; ++v4) {
                            float4 f = s4[v4];
                            if (RELU_IN) { f.x=fmaxf(f.x,0.f); f.y=fmaxf(f.y,0.f); f.z=fmaxf(f.z,0.f); f.w=fmaxf(f.w,0.f); }
                            vals[v4*4+0] = bf16e(f.x); vals[v4*4+1] = bf16e(f.y);
                            vals[v4*4+2] = bf16e(f.z); vals[v4*4+3] = bf16e(f.w);
                        }
                    } else {
#pragma unroll
                        for (int c = 0; c < 16; ++c) {
                            float f = (cb0 + c < CIN) ? feats[(size_t)id * CIN + cb0 + c] : 0.0f;
                            if (RELU_IN) f = fmaxf(f, 0.0f);
                            vals[c] = bf16e(f);
                        }
                    }
                } else {
#pragma unroll
                    for (int c = 0; c < 16; ++c) vals[c] = 0;
                }
#pragma unroll
                for (int c = 0; c < 16; ++c) sFT[(pt * 16 + c) * WST + k] = vals[c];
            }
            __syncthreads();

            // step1: per-point GEMM A_mt_cc[tap][c] = W_mt x featsT ; wave w -> pts 2w,2w+1
            {
                f32x4 a1[2] = {{0,0,0,0},{0,0,0,0}};
#pragma unroll
                for (int s = 0; s < 2; ++s) {
                    int kidx = s * 32 + kg * 8;
                    bool valid = (kidx < KN);
#pragma unroll
                    for (int pi = 0; pi < 2; ++pi) {
                        int p = 2 * w + pi;
                        short8 av = {0,0,0,0,0,0,0,0}, bv = {0,0,0,0,0,0,0,0};
                        if (valid) {
                            av = *(const short8*)(sW  + (p * 16 + n16) * WST + kidx);
                            bv = *(const short8*)(sFT + (p * 16 + n16) * WST + kidx);
                        }
                        a1[pi] = __builtin_amdgcn_mfma_f32_16x16x32_bf16(av, bv, a1[pi], 0, 0, 0);
                    }
                }
                // D[tap=(kg*4+r)][c=n16] -> sA2[pt][tap*16+c]
#pragma unroll
                for (int pi = 0; pi < 2; ++pi) {
                    int p = 2 * w + pi;
#pragma unroll
                    for (int r = 0; r < 4; ++r)
                        sA2[p * A2ST + (kg * 4 + r) * 16 + n16] = bf16e(a1[pi][r]);
                }
            }
            __syncthreads();

            // step2: acc += A2(16 pts x 256) * F2t(256 x DPAD); wave (dt, kh), guarded K-range
            {
                const unsigned short* gB =
                    F2t + ((size_t)(((mt * NCC + cc) * NT + dt) * 16 + n16)) * 256;
                const int s0 = kh * SPC;
                const int s1 = (s0 + SPC < S2) ? (s0 + SPC) : S2;
                for (int s2 = s0; s2 < s1; ++s2) {
                    int k2 = s2 * 32 + kg * 8;
                    short8 av = *(const short8*)(sA2 + n16 * A2ST + k2);
                    short8 bv = *(const short8*)(gB + k2);
                    acc = __builtin_amdgcn_mfma_f32_16x16x32_bf16(av, bv, acc, 0, 0, 0);
                }
            }
            __syncthreads();
        }
    }

    // self/dense branch: acc += relu(self feats) x FD
    if constexpr (HAS_SELF) {
        constexpr int NP = NCC / 2;
        for (int ccp = 0; ccp < NP; ++ccp) {
            if (tid < TM * 32) {
                int pt = tid / 32, c = tid & 31;
                int cin = ccp * 32 + c;
                float f = (cin < CIN) ? feats[(size_t)(pt0 + pt) * CIN + cin] : 0.0f;
                if (RELU_IN) f = fmaxf(f, 0.0f);
                sA3[pt * 40 + c] = bf16e(f);
            }
            __syncthreads();
            if (ccp % SPLITK == kh) {
                short8 av = *(const short8*)(sA3 + n16 * 40 + kg * 8);
                short8 bv = *(const short8*)(FD + (size_t)(dt * 16 + n16) * CINP + ccp * 32 + kg * 8);
                acc = __builtin_amdgcn_mfma_f32_16x16x32_bf16(av, bv, acc, 0, 0, 0);
            }
            __syncthreads();
        }
    }

    // epilogue: split-K combine + bias + output modes
#pragma unroll
    for (int r = 0; r < 4; ++r) sEpi[(w * 64 + lane) * 4 + r] = acc[r];
    __syncthreads();

    if (w < NT) {
        float sum[4];
#pragma unroll
        for (int r = 0; r < 4; ++r) {
            float s = 0.0f;
#pragma unroll
            for (int k = 0; k < SPLITK; ++k)
                s += sEpi[((k * NT + w) * 64 + lane) * 4 + r];
            sum[r] = s;
        }
        int d = w * 16 + n16;
        if (d < COUT) {
            float b = bias[d];
#pragma unroll
            for (int r = 0; r < 4; ++r) {
                int pt = kg * 4 + r;
                int q  = pt0 + pt;
                float y = sum[r] + b;
                if constexpr (OUT_MODE == 0) {
                    outp[q * out_stride + out_off + d] = y;
                } else if constexpr (OUT_MODE == 1) {
                    outp[q * COUT + d] = y;
                } else if constexpr (OUT_MODE == 2) {
                    outp[q * COUT + d] = y + resid[q * COUT + d];
                } else {
                    float corr = y * (1.0f / 128.0f);
                    float pn   = qpos[q * 3 + d];
                    float pc   = pn + corr;
                    outp[q * 3 + d]          = pc;
                    outp[NF * 3 + q * 3 + d] = (pc - pos0[q * 3 + d]) * (1.0f / 0.02f);
                }
            }
        }
    }
}

// ---------------------------------------------------------------------------
// host launcher
// ---------------------------------------------------------------------------
extern "C" void kernel_launch(void* const* d_in, const int* in_sizes, int n_in,
                              void* d_out, int out_size, void* d_ws, size_t ws_size,
                              hipStream_t stream)
{
    (void)in_sizes; (void)n_in; (void)out_size; (void)ws_size;

    const float* pos       = (const float*)d_in[0];
    const float* vel       = (const float*)d_in[1];
    const float* box       = (const float*)d_in[2];
    const float* box_feats = (const float*)d_in[3];
    const int*   nbrf      = (const int*)d_in[4];
    const int*   nbrb      = (const int*)d_in[5];
    const float* cf0_w = (const float*)d_in[6];
    const float* cf0_b = (const float*)d_in[7];
    const float* co0_w = (const float*)d_in[8];
    const float* co0_b = (const float*)d_in[9];
    const float* d0_w  = (const float*)d_in[10];
    const float* d0_b  = (const float*)d_in[11];
    const float* c1_w  = (const float*)d_in[12];
    const float* c1_b  = (const float*)d_in[13];
    const float* d1_w  = (const float*)d_in[14];
    const float* d1_b  = (const float*)d_in[15];
    const float* c2_w  = (const float*)d_in[16];
    const float* c2_b  = (const float*)d_in[17];
    const float* d2_w  = (const float*)d_in[18];
    const float* d2_b  = (const float*)d_in[19];
    const float* c3_w  = (const float*)d_in[20];
    const float* c3_b  = (const float*)d_in[21];
    const float* d3_w  = (const float*)d_in[22];
    const float* d3_b  = (const float*)d_in[23];

    char* ws = (char*)d_ws;
    float*          POSNEW = (float*)(ws + 0);        // 98304
    float*          FEATS0 = (float*)(ws + 98304);    // 131072
    float*          X      = (float*)(ws + 229376);   // 8192*96*4 = 3145728
    float*          X1     = (float*)(ws + 3375104);  // 2097152
    float*          X2     = (float*)(ws + 5472256);  // 2097152
    unsigned short* F2T1   = (unsigned short*)(ws + 7569408); // 786432
    unsigned short* F2T2   = (unsigned short*)(ws + 8355840); // 524288
    unsigned short* F2T3   = (unsigned short*)(ws + 8880128); // 131072
    unsigned short* F2Tf   = (unsigned short*)(ws + 9011200); // 65536
    unsigned short* F2To   = (unsigned short*)(ws + 9076736); // 65536
    unsigned short* FD1    = (unsigned short*)(ws + 9142272); // 12288
    unsigned short* FD2    = (unsigned short*)(ws + 9154560); // 8192
    unsigned short* FD3    = (unsigned short*)(ws + 9162752); // 2048
    float*          B1     = (float*)(ws + 9164800);
    float*          B2     = (float*)(ws + 9165056);
    float*          B3     = (float*)(ws + 9165312);
    float*          Bf0    = (float*)(ws + 9165568);
    float*          Bo0    = (float*)(ws + 9165824);

    float* out_f = (float*)d_out;

    // packs: <CIN, COUT, HAS_SELF>; grid covers F2t + FD
    pn_pack<96, 64, 1><<<(4*6*4*16*256 + 64*96 + 255) / 256, 256, 0, stream>>>(c1_w, d1_w, c1_b, d1_b, F2T1, FD1, B1);
    pn_pack<64, 64, 1><<<(4*4*4*16*256 + 64*64 + 255) / 256, 256, 0, stream>>>(c2_w, d2_w, c2_b, d2_b, F2T2, FD2, B2);
    pn_pack<64, 3, 1><<<(4*4*1*16*256 + 16*64 + 255) / 256, 256, 0, stream>>>(c3_w, d3_w, c3_b, d3_b, F2T3, FD3, B3);
    pn_pack<4, 32, 0><<<(4*1*2*16*256 + 255) / 256, 256, 0, stream>>>(cf0_w, nullptr, cf0_b, nullptr, F2Tf, nullptr, Bf0);
    pn_pack<3, 32, 0><<<(4*1*2*16*256 + 255) / 256, 256, 0, stream>>>(co0_w, nullptr, co0_b, nullptr, F2To, nullptr, Bo0);

    pn_prep<<<(NF + 255) / 256, 256, 0, stream>>>(pos, vel, nbrf, d0_w, d0_b,
                                                  POSNEW, FEATS0, X, out_f + NF * 6);

    // convs: <CIN, COUT, HAS_SELF, RELU_IN, OUT_MODE>, grid NF/16, 512 thr
    pn_cconv<4, 32, 0, 0, 0><<<NF / TM, 512, 0, stream>>>(
        POSNEW, POSNEW, FEATS0, nbrf, F2Tf, nullptr, Bf0, nullptr, X, nullptr, 96, 32);
    pn_cconv<3, 32, 0, 0, 0><<<NF / TM, 512, 0, stream>>>(
        POSNEW, box, box_feats, nbrb, F2To, nullptr, Bo0, nullptr, X, nullptr, 96, 0);
    pn_cconv<96, 64, 1, 1, 1><<<NF / TM, 512, 0, stream>>>(
        POSNEW, POSNEW, X, nbrf, F2T1, FD1, B1, nullptr, X1, nullptr, 0, 0);
    pn_cconv<64, 64, 1, 1, 2><<<NF / TM, 512, 0, stream>>>(
        POSNEW, POSNEW, X1, nbrf, F2T2, FD2, B2, X1, X2, nullptr, 0, 0);
    pn_cconv<64, 3, 1, 1, 3><<<NF / TM, 512, 0, stream>>>(
        POSNEW, POSNEW, X2, nbrf, F2T3, FD3, B3, nullptr, out_f, pos, 0, 0);
}

// Round 9
// 395.837 us; speedup vs baseline: 7.3568x; 1.3261x over previous
//
#include <hip/hip_runtime.h>

#define NF 8192
#define KN 48
#define TM 8

typedef __attribute__((ext_vector_type(8))) short short8;
typedef __attribute__((ext_vector_type(4))) float f32x4;

__device__ __forceinline__ unsigned short bf16e(float f) {
    return (unsigned short)((__float_as_uint(f) + 0x8000u) >> 16);
}

// ---------------------------------------------------------------------------
// geometry: ball->cube + trilinear corner weights for one neighbor
// packs 8 entries of (tap<<16 | bf16(weight)) into g[0..7]
// ---------------------------------------------------------------------------
__device__ __forceinline__ void pn_geom(float rx, float ry, float rz, unsigned* g)
{
    float d2  = rx * rx + ry * ry + rz * rz;
    float om  = 1.0f - d2;
    float win = om * om * om;
    win = fminf(fmaxf(win, 0.0f), 1.0f);

    float rxy2 = rx * rx + ry * ry;
    float rho  = sqrtf(rxy2 + rz * rz + 1e-8f);
    float rxyv = sqrtf(rxy2 + 1e-8f);
    bool  pole = (rxy2 <= 1.25f * rz * rz);
    float s    = pole ? sqrtf(3.0f * rho / (rho + fabsf(rz))) : (rho / rxyv);
    float cx = rx * s, cy = ry * s;
    float sgnz = (rz > 0.0f) ? 1.0f : ((rz < 0.0f) ? -1.0f : 0.0f);
    float cz   = pole ? sgnz * rho : 1.5f * rz;

    float rr   = sqrtf(cx * cx + cy * cy + 1e-8f);
    bool  cond = fabsf(cx) >= fabsf(cy);
    float sx = (cx >= 0.0f) ? 1.0f : -1.0f;
    float sy = (cy >= 0.0f) ? 1.0f : -1.0f;
    float safecx = (fabsf(cx) > 1e-8f) ? cx : 1.0f;
    float safecy = (fabsf(cy) > 1e-8f) ? cy : 1.0f;
    const float C4PI = 1.2732395447351628f;
    float u = cond ? (sx * rr) : (sy * C4PI * rr * atanf(cx / safecy));
    float v = cond ? (sx * C4PI * rr * atanf(cy / safecx)) : (sy * rr);
    if (rho < 1e-6f) { u = 0.0f; v = 0.0f; cz = 0.0f; }

    float tx = fminf(fmaxf((u  * 0.5f + 0.5f) * 3.0f, 0.0f), 3.0f);
    float ty = fminf(fmaxf((v  * 0.5f + 0.5f) * 3.0f, 0.0f), 3.0f);
    float tz = fminf(fmaxf((cz * 0.5f + 0.5f) * 3.0f, 0.0f), 3.0f);
    int ix = (int)floorf(tx); ix = ix < 0 ? 0 : (ix > 2 ? 2 : ix);
    int iy = (int)floorf(ty); iy = iy < 0 ? 0 : (iy > 2 ? 2 : iy);
    int iz = (int)floorf(tz); iz = iz < 0 ? 0 : (iz > 2 ? 2 : iz);
    float fx = tx - (float)ix, fy = ty - (float)iy, fz = tz - (float)iz;
    float wx0 = 1.0f - fx, wy0 = 1.0f - fy, wz0 = 1.0f - fz;

#pragma unroll
    for (int dx = 0; dx < 2; ++dx)
#pragma unroll
        for (int dy = 0; dy < 2; ++dy)
#pragma unroll
            for (int dz = 0; dz < 2; ++dz) {
                float w = (dx ? fx : wx0) * (dy ? fy : wy0) * (dz ? fz : wz0) * win;
                int tap = ((ix + dx) << 4) + ((iy + dy) << 2) + (iz + dz);
                g[(dx << 2) | (dy << 1) | dz] = ((unsigned)tap << 16) | (unsigned)bf16e(w);
            }
}

// ---------------------------------------------------------------------------
// prep: vel_new/pos_new, fluid feats, neighbor count, dense d0 branch
// ---------------------------------------------------------------------------
__global__ void __launch_bounds__(256) pn_prep(
    const float* __restrict__ pos, const float* __restrict__ vel,
    const int* __restrict__ nbrf,
    const float* __restrict__ d0w, const float* __restrict__ d0b,
    float* __restrict__ pos_new, float* __restrict__ feats0,
    float* __restrict__ X, float* __restrict__ nfn)
{
    int t = blockIdx.x * 256 + threadIdx.x;
    if (t >= NF) return;
    float vx = vel[t * 3 + 0], vy = vel[t * 3 + 1], vz = vel[t * 3 + 2];
    float vnx = vx, vny = vy - 9.81f * 0.02f, vnz = vz;
    float pnx = pos[t * 3 + 0] + (vx + vnx) * 0.01f;
    float pny = pos[t * 3 + 1] + (vy + vny) * 0.01f;
    float pnz = pos[t * 3 + 2] + (vz + vnz) * 0.01f;
    pos_new[t * 3 + 0] = pnx; pos_new[t * 3 + 1] = pny; pos_new[t * 3 + 2] = pnz;
    feats0[t * 4 + 0] = 1.0f; feats0[t * 4 + 1] = vnx;
    feats0[t * 4 + 2] = vny;  feats0[t * 4 + 3] = vnz;
    int cnt = 0;
    for (int k = 0; k < KN; ++k) cnt += (nbrf[t * KN + k] >= 0) ? 1 : 0;
    nfn[t] = (float)cnt;
    for (int j = 0; j < 32; ++j) {
        float s = d0b[j] + d0w[0 * 32 + j] + vnx * d0w[1 * 32 + j]
                + vny * d0w[2 * 32 + j] + vnz * d0w[3 * 32 + j];
        X[t * 96 + 64 + j] = s;
    }
}

// ---------------------------------------------------------------------------
// pack:  F2t[mt][cc][dt][dd 16][k2=tl*16+cl : 256]  (B^T, K contiguous, bf16)
//        FD[d][CINP] (dense branch, B^T), B = cb (+db)
// ---------------------------------------------------------------------------
template <int CIN, int COUT, int HAS_SELF>
__global__ void __launch_bounds__(256) pn_pack(
    const float* __restrict__ cw, const float* __restrict__ dw,
    const float* __restrict__ cb, const float* __restrict__ db,
    unsigned short* __restrict__ F2t, unsigned short* __restrict__ FD,
    float* __restrict__ B)
{
    constexpr int CINP = ((CIN + 15) / 16) * 16;
    constexpr int NCC  = CINP / 16;
    constexpr int DPAD = ((COUT + 15) / 16) * 16;
    constexpr int NT   = DPAD / 16;
    const int total1 = 4 * NCC * NT * 16 * 256;
    const int total2 = HAS_SELF ? DPAD * CINP : 0;
    int i = blockIdx.x * 256 + threadIdx.x;
    if (i < total1) {
        int k2 = i & 255;
        int q  = i >> 8;
        int dd = q & 15; q >>= 4;
        int dt = q % NT; q /= NT;
        int cc = q % NCC;
        int mt = q / NCC;
        int t   = mt * 16 + (k2 >> 4);
        int cin = cc * 16 + (k2 & 15);
        int d   = dt * 16 + dd;
        float v = 0.0f;
        if (cin < CIN && d < COUT) v = cw[((size_t)t * CIN + cin) * COUT + d];
        F2t[i] = bf16e(v);
    } else if (i < total1 + total2) {
        int j = i - total1;
        int d = j / CINP, c = j % CINP;
        float v = 0.0f;
        if (c < CIN && d < COUT) v = dw[(size_t)c * COUT + d];
        FD[j] = bf16e(v);
    }
    if (i < COUT) B[i] = cb[i] + (HAS_SELF ? db[i] : 0.0f);
}

// ---------------------------------------------------------------------------
// fused CConv, all-MFMA, W64-persistent:
//   phase0: geometry writes dense W64[pt][64 taps][48 k] directly (write-once)
//   per cc: stage featsT once; per mt: step1 MFMA (W-slice x featsT) -> A2,
//           step2 MFMA (A2 x F2t) -> acc  [guarded split-K]
//   self/dense branch: relu(self feats) MFMA with FD
// NOTE: MFMA is wave-cooperative — never branch around it with a
//       lane-divergent condition; zero the fragments instead (round-8 bug).
// OUT_MODE: 0 = X-slice, 1 = plain, 2 = +resid, 3 = final pos/vel
// ---------------------------------------------------------------------------
template <int CIN, int COUT, int HAS_SELF, int RELU_IN, int OUT_MODE>
__global__ void __launch_bounds__(512, 4) pn_cconv(
    const float* __restrict__ qpos, const float* __restrict__ ppos,
    const float* __restrict__ feats, const int* __restrict__ nbr,
    const unsigned short* __restrict__ F2t, const unsigned short* __restrict__ FD,
    const float* __restrict__ bias,
    const float* __restrict__ resid, float* __restrict__ outp,
    const float* __restrict__ pos0, int out_stride, int out_off)
{
    constexpr int CINP   = ((CIN + 15) / 16) * 16;
    constexpr int NCC    = CINP / 16;
    constexpr int DPAD   = ((COUT + 15) / 16) * 16;
    constexpr int NT     = DPAD / 16;
    constexpr int SPLITK = 8 / NT;
    constexpr int S2     = 8;                       // 32-wide K-steps per (mt,cc)
    constexpr int SPC    = (S2 + SPLITK - 1) / SPLITK;
    constexpr int WST    = 56;    // row stride (bf16), 112B, 16B-aligned
    constexpr int A2ST   = 264;   // A2 row stride (528B, 16B-aligned)

    __shared__ int      sI[TM * KN];
    __shared__ int      sKN[TM];
    __shared__ __align__(16) unsigned short sW [TM * 64 * WST];   // 57344B, persistent
    __shared__ __align__(16) unsigned short sFT[TM * 16 * WST];   // 14336B (aliased late)
    __shared__ __align__(16) unsigned short sA2[TM * A2ST];       // 4224B

    float*          sEpi = (float*)sFT;            // 8192B, used after sFT dead
    unsigned short* sA3  = sFT + 4096;             // self staging, after sFT dead

    const int tid  = threadIdx.x;
    const int w    = tid >> 6;
    const int lane = tid & 63;
    const int n16  = lane & 15;
    const int kg   = lane >> 4;
    const int pt0  = blockIdx.x * TM;
    const int dt   = w % NT;
    const int kh   = w / NT;

    if (tid < TM) sKN[tid] = KN;
    // zero W64 once
    {
        uint4 z4 = make_uint4(0, 0, 0, 0);
        for (int i = tid; i < TM * 64 * WST / 8; i += 512) ((uint4*)sW)[i] = z4;
    }
    __syncthreads();

    // phase 0: geometry -> scatter into persistent W64 (write-once, no atomics)
    for (int e = tid; e < TM * KN; e += 512) {
        int lp = e / KN, k = e - lp * KN;
        int q  = pt0 + lp;
        int id = nbr[q * KN + k];
        if (id >= 0) {
            sI[e] = id;
            float rx = (ppos[id * 3 + 0] - qpos[q * 3 + 0]) * (1.0f / 0.1125f);
            float ry = (ppos[id * 3 + 1] - qpos[q * 3 + 1]) * (1.0f / 0.1125f);
            float rz = (ppos[id * 3 + 2] - qpos[q * 3 + 2]) * (1.0f / 0.1125f);
            unsigned g[8];
            pn_geom(rx, ry, rz, g);
#pragma unroll
            for (int j = 0; j < 8; ++j)
                sW[(lp * 64 + (int)(g[j] >> 16)) * WST + k] = (unsigned short)(g[j] & 0xffffu);
        } else {
            atomicMin(&sKN[lp], k);
        }
    }

    f32x4 acc = {0.0f, 0.0f, 0.0f, 0.0f};
    __syncthreads();

    for (int cc = 0; cc < NCC; ++cc) {
        const int cb0 = cc * 16;

        // stage transposed features ONCE per cc: sFT[pt][c][k]
        for (int e = tid; e < TM * KN; e += 512) {
            int pt = e / KN, k = e - pt * KN;
            unsigned short vals[16];
            if (k < sKN[pt]) {
                int id = sI[e];
                if constexpr (CIN % 16 == 0) {
                    const float4* s4 = (const float4*)(feats + (size_t)id * CIN + cb0);
#pragma unroll
                    for (int v4 = 0; v4 < 4; ++v4) {
                        float4 f = s4[v4];
                        if (RELU_IN) { f.x=fmaxf(f.x,0.f); f.y=fmaxf(f.y,0.f); f.z=fmaxf(f.z,0.f); f.w=fmaxf(f.w,0.f); }
                        vals[v4*4+0] = bf16e(f.x); vals[v4*4+1] = bf16e(f.y);
                        vals[v4*4+2] = bf16e(f.z); vals[v4*4+3] = bf16e(f.w);
                    }
                } else {
#pragma unroll
                    for (int c = 0; c < 16; ++c) {
                        float f = (cb0 + c < CIN) ? feats[(size_t)id * CIN + cb0 + c] : 0.0f;
                        if (RELU_IN) f = fmaxf(f, 0.0f);
                        vals[c] = bf16e(f);
                    }
                }
            } else {
#pragma unroll
                for (int c = 0; c < 16; ++c) vals[c] = 0;
            }
#pragma unroll
            for (int c = 0; c < 16; ++c) sFT[(pt * 16 + c) * WST + k] = vals[c];
        }
        __syncthreads();

        for (int mt = 0; mt < 4; ++mt) {
            // step1: per-point GEMM A2[tap][c] = W64-slice x featsT; wave w -> pt w
            // MFMA issued unconditionally; invalid K-lanes feed zero fragments.
            {
                f32x4 a1 = {0.0f, 0.0f, 0.0f, 0.0f};
                const short8 z8 = {0,0,0,0,0,0,0,0};
#pragma unroll
                for (int s = 0; s < 2; ++s) {
                    int kidx = s * 32 + kg * 8;
                    short8 av = z8, bv = z8;
                    if (kidx < KN) {
                        av = *(const short8*)(sW  + (w * 64 + mt * 16 + n16) * WST + kidx);
                        bv = *(const short8*)(sFT + (w * 16 + n16) * WST + kidx);
                    }
                    a1 = __builtin_amdgcn_mfma_f32_16x16x32_bf16(av, bv, a1, 0, 0, 0);
                }
#pragma unroll
                for (int r = 0; r < 4; ++r)
                    sA2[w * A2ST + (kg * 4 + r) * 16 + n16] = bf16e(a1[r]);
            }
            __syncthreads();

            // step2: acc += A2(TM pts x 256) * F2t(256 x DPAD); wave (dt,kh), guarded
            {
                const unsigned short* gB =
                    F2t + ((size_t)(((mt * NCC + cc) * NT + dt) * 16 + n16)) * 256;
                const int s0 = kh * SPC;
                const int s1 = (s0 + SPC < S2) ? (s0 + SPC) : S2;
                const short8 z8 = {0,0,0,0,0,0,0,0};
                for (int s2 = s0; s2 < s1; ++s2) {
                    int k2 = s2 * 32 + kg * 8;
                    short8 av = (n16 < TM) ? *(const short8*)(sA2 + n16 * A2ST + k2) : z8;
                    short8 bv = *(const short8*)(gB + k2);
                    acc = __builtin_amdgcn_mfma_f32_16x16x32_bf16(av, bv, acc, 0, 0, 0);
                }
            }
            __syncthreads();
        }
    }

    // self/dense branch: acc += relu(self feats) x FD   (sA3 aliases dead sFT)
    if constexpr (HAS_SELF) {
        constexpr int NP = NCC / 2;
        for (int ccp = 0; ccp < NP; ++ccp) {
            if (tid < TM * 32) {
                int pt = tid / 32, c = tid & 31;
                int cin = ccp * 32 + c;
                float f = (cin < CIN) ? feats[(size_t)(pt0 + pt) * CIN + cin] : 0.0f;
                if (RELU_IN) f = fmaxf(f, 0.0f);
                sA3[pt * 40 + c] = bf16e(f);
            }
            __syncthreads();
            if (ccp % SPLITK == kh) {    // wave-uniform condition: safe around MFMA
                const short8 z8 = {0,0,0,0,0,0,0,0};
                short8 av = (n16 < TM) ? *(const short8*)(sA3 + n16 * 40 + kg * 8) : z8;
                short8 bv = *(const short8*)(FD + (size_t)(dt * 16 + n16) * CINP + ccp * 32 + kg * 8);
                acc = __builtin_amdgcn_mfma_f32_16x16x32_bf16(av, bv, acc, 0, 0, 0);
            }
            __syncthreads();
        }
    }

    // epilogue: split-K combine + bias + output modes (sEpi aliases dead sFT)
#pragma unroll
    for (int r = 0; r < 4; ++r) sEpi[(w * 64 + lane) * 4 + r] = acc[r];
    __syncthreads();

    if (w < NT) {
        float sum[4];
#pragma unroll
        for (int r = 0; r < 4; ++r) {
            float s = 0.0f;
#pragma unroll
            for (int k = 0; k < SPLITK; ++k)
                s += sEpi[((k * NT + w) * 64 + lane) * 4 + r];
            sum[r] = s;
        }
        int d = w * 16 + n16;
        if (d < COUT) {
            float b = bias[d];
#pragma unroll
            for (int r = 0; r < 4; ++r) {
                int pt = kg * 4 + r;
                if (pt < TM) {
                    int q = pt0 + pt;
                    float y = sum[r] + b;
                    if constexpr (OUT_MODE == 0) {
                        outp[q * out_stride + out_off + d] = y;
                    } else if constexpr (OUT_MODE == 1) {
                        outp[q * COUT + d] = y;
                    } else if constexpr (OUT_MODE == 2) {
                        outp[q * COUT + d] = y + resid[q * COUT + d];
                    } else {
                        float corr = y * (1.0f / 128.0f);
                        float pn   = qpos[q * 3 + d];
                        float pc   = pn + corr;
                        outp[q * 3 + d]          = pc;
                        outp[NF * 3 + q * 3 + d] = (pc - pos0[q * 3 + d]) * (1.0f / 0.02f);
                    }
                }
            }
        }
    }
}

// ---------------------------------------------------------------------------
// host launcher
// ---------------------------------------------------------------------------
extern "C" void kernel_launch(void* const* d_in, const int* in_sizes, int n_in,
                              void* d_out, int out_size, void* d_ws, size_t ws_size,
                              hipStream_t stream)
{
    (void)in_sizes; (void)n_in; (void)out_size; (void)ws_size;

    const float* pos       = (const float*)d_in[0];
    const float* vel       = (const float*)d_in[1];
    const float* box       = (const float*)d_in[2];
    const float* box_feats = (const float*)d_in[3];
    const int*   nbrf      = (const int*)d_in[4];
    const int*   nbrb      = (const int*)d_in[5];
    const float* cf0_w = (const float*)d_in[6];
    const float* cf0_b = (const float*)d_in[7];
    const float* co0_w = (const float*)d_in[8];
    const float* co0_b = (const float*)d_in[9];
    const float* d0_w  = (const float*)d_in[10];
    const float* d0_b  = (const float*)d_in[11];
    const float* c1_w  = (const float*)d_in[12];
    const float* c1_b  = (const float*)d_in[13];
    const float* d1_w  = (const float*)d_in[14];
    const float* d1_b  = (const float*)d_in[15];
    const float* c2_w  = (const float*)d_in[16];
    const float* c2_b  = (const float*)d_in[17];
    const float* d2_w  = (const float*)d_in[18];
    const float* d2_b  = (const float*)d_in[19];
    const float* c3_w  = (const float*)d_in[20];
    const float* c3_b  = (const float*)d_in[21];
    const float* d3_w  = (const float*)d_in[22];
    const float* d3_b  = (const float*)d_in[23];

    char* ws = (char*)d_ws;
    float*          POSNEW = (float*)(ws + 0);        // 98304
    float*          FEATS0 = (float*)(ws + 98304);    // 131072
    float*          X      = (float*)(ws + 229376);   // 8192*96*4 = 3145728
    float*          X1     = (float*)(ws + 3375104);  // 2097152
    float*          X2     = (float*)(ws + 5472256);  // 2097152
    unsigned short* F2T1   = (unsigned short*)(ws + 7569408); // 786432
    unsigned short* F2T2   = (unsigned short*)(ws + 8355840); // 524288
    unsigned short* F2T3   = (unsigned short*)(ws + 8880128); // 131072
    unsigned short* F2Tf   = (unsigned short*)(ws + 9011200); // 65536
    unsigned short* F2To   = (unsigned short*)(ws + 9076736); // 65536
    unsigned short* FD1    = (unsigned short*)(ws + 9142272); // 12288
    unsigned short* FD2    = (unsigned short*)(ws + 9154560); // 8192
    unsigned short* FD3    = (unsigned short*)(ws + 9162752); // 2048
    float*          B1     = (float*)(ws + 9164800);
    float*          B2     = (float*)(ws + 9165056);
    float*          B3     = (float*)(ws + 9165312);
    float*          Bf0    = (float*)(ws + 9165568);
    float*          Bo0    = (float*)(ws + 9165824);

    float* out_f = (float*)d_out;

    // packs: <CIN, COUT, HAS_SELF>; grid covers F2t + FD
    pn_pack<96, 64, 1><<<(4*6*4*16*256 + 64*96 + 255) / 256, 256, 0, stream>>>(c1_w, d1_w, c1_b, d1_b, F2T1, FD1, B1);
    pn_pack<64, 64, 1><<<(4*4*4*16*256 + 64*64 + 255) / 256, 256, 0, stream>>>(c2_w, d2_w, c2_b, d2_b, F2T2, FD2, B2);
    pn_pack<64, 3, 1><<<(4*4*1*16*256 + 16*64 + 255) / 256, 256, 0, stream>>>(c3_w, d3_w, c3_b, d3_b, F2T3, FD3, B3);
    pn_pack<4, 32, 0><<<(4*1*2*16*256 + 255) / 256, 256, 0, stream>>>(cf0_w, nullptr, cf0_b, nullptr, F2Tf, nullptr, Bf0);
    pn_pack<3, 32, 0><<<(4*1*2*16*256 + 255) / 256, 256, 0, stream>>>(co0_w, nullptr, co0_b, nullptr, F2To, nullptr, Bo0);

    pn_prep<<<(NF + 255) / 256, 256, 0, stream>>>(pos, vel, nbrf, d0_w, d0_b,
                                                  POSNEW, FEATS0, X, out_f + NF * 6);

    // convs: <CIN, COUT, HAS_SELF, RELU_IN, OUT_MODE>, grid NF/8, 512 thr
    pn_cconv<4, 32, 0, 0, 0><<<NF / TM, 512, 0, stream>>>(
        POSNEW, POSNEW, FEATS0, nbrf, F2Tf, nullptr, Bf0, nullptr, X, nullptr, 96, 32);
    pn_cconv<3, 32, 0, 0, 0><<<NF / TM, 512, 0, stream>>>(
        POSNEW, box, box_feats, nbrb, F2To, nullptr, Bo0, nullptr, X, nullptr, 96, 0);
    pn_cconv<96, 64, 1, 1, 1><<<NF / TM, 512, 0, stream>>>(
        POSNEW, POSNEW, X, nbrf, F2T1, FD1, B1, nullptr, X1, nullptr, 0, 0);
    pn_cconv<64, 64, 1, 1, 2><<<NF / TM, 512, 0, stream>>>(
        POSNEW, POSNEW, X1, nbrf, F2T2, FD2, B2, X1, X2, nullptr, 0, 0);
    pn_cconv<64, 3, 1, 1, 3><<<NF / TM, 512, 0, stream>>>(
        POSNEW, POSNEW, X2, nbrf, F2T3, FD3, B3, nullptr, out_f, pos, 0, 0);
}

// Round 10
// 369.185 us; speedup vs baseline: 7.8879x; 1.0722x over previous
//
#include <hip/hip_runtime.h>

#define NF 8192
#define KN 48
#define TM 8

typedef __attribute__((ext_vector_type(8))) short short8;
typedef __attribute__((ext_vector_type(4))) float f32x4;

__device__ __forceinline__ unsigned short bf16e(float f) {
    return (unsigned short)((__float_as_uint(f) + 0x8000u) >> 16);
}

// ---------------------------------------------------------------------------
// geometry: ball->cube + trilinear corner weights for one neighbor
// packs 8 entries of (tap<<16 | bf16(weight)) into g[0..7]
// ---------------------------------------------------------------------------
__device__ __forceinline__ void pn_geom(float rx, float ry, float rz, unsigned* g)
{
    float d2  = rx * rx + ry * ry + rz * rz;
    float om  = 1.0f - d2;
    float win = om * om * om;
    win = fminf(fmaxf(win, 0.0f), 1.0f);

    float rxy2 = rx * rx + ry * ry;
    float rho  = sqrtf(rxy2 + rz * rz + 1e-8f);
    float rxyv = sqrtf(rxy2 + 1e-8f);
    bool  pole = (rxy2 <= 1.25f * rz * rz);
    float s    = pole ? sqrtf(3.0f * rho / (rho + fabsf(rz))) : (rho / rxyv);
    float cx = rx * s, cy = ry * s;
    float sgnz = (rz > 0.0f) ? 1.0f : ((rz < 0.0f) ? -1.0f : 0.0f);
    float cz   = pole ? sgnz * rho : 1.5f * rz;

    float rr   = sqrtf(cx * cx + cy * cy + 1e-8f);
    bool  cond = fabsf(cx) >= fabsf(cy);
    float sx = (cx >= 0.0f) ? 1.0f : -1.0f;
    float sy = (cy >= 0.0f) ? 1.0f : -1.0f;
    float safecx = (fabsf(cx) > 1e-8f) ? cx : 1.0f;
    float safecy = (fabsf(cy) > 1e-8f) ? cy : 1.0f;
    const float C4PI = 1.2732395447351628f;
    float u = cond ? (sx * rr) : (sy * C4PI * rr * atanf(cx / safecy));
    float v = cond ? (sx * C4PI * rr * atanf(cy / safecx)) : (sy * rr);
    if (rho < 1e-6f) { u = 0.0f; v = 0.0f; cz = 0.0f; }

    float tx = fminf(fmaxf((u  * 0.5f + 0.5f) * 3.0f, 0.0f), 3.0f);
    float ty = fminf(fmaxf((v  * 0.5f + 0.5f) * 3.0f, 0.0f), 3.0f);
    float tz = fminf(fmaxf((cz * 0.5f + 0.5f) * 3.0f, 0.0f), 3.0f);
    int ix = (int)floorf(tx); ix = ix < 0 ? 0 : (ix > 2 ? 2 : ix);
    int iy = (int)floorf(ty); iy = iy < 0 ? 0 : (iy > 2 ? 2 : iy);
    int iz = (int)floorf(tz); iz = iz < 0 ? 0 : (iz > 2 ? 2 : iz);
    float fx = tx - (float)ix, fy = ty - (float)iy, fz = tz - (float)iz;
    float wx0 = 1.0f - fx, wy0 = 1.0f - fy, wz0 = 1.0f - fz;

#pragma unroll
    for (int dx = 0; dx < 2; ++dx)
#pragma unroll
        for (int dy = 0; dy < 2; ++dy)
#pragma unroll
            for (int dz = 0; dz < 2; ++dz) {
                float w = (dx ? fx : wx0) * (dy ? fy : wy0) * (dz ? fz : wz0) * win;
                int tap = ((ix + dx) << 4) + ((iy + dy) << 2) + (iz + dz);
                g[(dx << 2) | (dy << 1) | dz] = ((unsigned)tap << 16) | (unsigned)bf16e(w);
            }
}

// ---------------------------------------------------------------------------
// prep: vel_new/pos_new, fluid feats, neighbor count, dense d0 branch
// ---------------------------------------------------------------------------
__global__ void __launch_bounds__(256) pn_prep(
    const float* __restrict__ pos, const float* __restrict__ vel,
    const int* __restrict__ nbrf,
    const float* __restrict__ d0w, const float* __restrict__ d0b,
    float* __restrict__ pos_new, float* __restrict__ feats0,
    float* __restrict__ X, float* __restrict__ nfn)
{
    int t = blockIdx.x * 256 + threadIdx.x;
    if (t >= NF) return;
    float vx = vel[t * 3 + 0], vy = vel[t * 3 + 1], vz = vel[t * 3 + 2];
    float vnx = vx, vny = vy - 9.81f * 0.02f, vnz = vz;
    float pnx = pos[t * 3 + 0] + (vx + vnx) * 0.01f;
    float pny = pos[t * 3 + 1] + (vy + vny) * 0.01f;
    float pnz = pos[t * 3 + 2] + (vz + vnz) * 0.01f;
    pos_new[t * 3 + 0] = pnx; pos_new[t * 3 + 1] = pny; pos_new[t * 3 + 2] = pnz;
    feats0[t * 4 + 0] = 1.0f; feats0[t * 4 + 1] = vnx;
    feats0[t * 4 + 2] = vny;  feats0[t * 4 + 3] = vnz;
    int cnt = 0;
    for (int k = 0; k < KN; ++k) cnt += (nbrf[t * KN + k] >= 0) ? 1 : 0;
    nfn[t] = (float)cnt;
    for (int j = 0; j < 32; ++j) {
        float s = d0b[j] + d0w[0 * 32 + j] + vnx * d0w[1 * 32 + j]
                + vny * d0w[2 * 32 + j] + vnz * d0w[3 * 32 + j];
        X[t * 96 + 64 + j] = s;
    }
}

// ---------------------------------------------------------------------------
// pack:  F2t[cc][dt][dd 16][k2 = tap*16+cl : 1024]  (B^T, K contiguous, bf16)
//        FD[d][CINP] (dense branch, B^T), B = cb (+db)
// ---------------------------------------------------------------------------
template <int CIN, int COUT, int HAS_SELF>
__global__ void __launch_bounds__(256) pn_pack(
    const float* __restrict__ cw, const float* __restrict__ dw,
    const float* __restrict__ cb, const float* __restrict__ db,
    unsigned short* __restrict__ F2t, unsigned short* __restrict__ FD,
    float* __restrict__ B)
{
    constexpr int CINP = ((CIN + 15) / 16) * 16;
    constexpr int NCC  = CINP / 16;
    constexpr int DPAD = ((COUT + 15) / 16) * 16;
    constexpr int NT   = DPAD / 16;
    const int total1 = NCC * NT * 16 * 1024;
    const int total2 = HAS_SELF ? DPAD * CINP : 0;
    int i = blockIdx.x * 256 + threadIdx.x;
    if (i < total1) {
        int k2 = i & 1023;
        int q  = i >> 10;
        int dd = q & 15; q >>= 4;
        int dt = q % NT;
        int cc = q / NT;
        int t   = k2 >> 4;
        int cin = cc * 16 + (k2 & 15);
        int d   = dt * 16 + dd;
        float v = 0.0f;
        if (cin < CIN && d < COUT) v = cw[((size_t)t * CIN + cin) * COUT + d];
        F2t[i] = bf16e(v);
    } else if (i < total1 + total2) {
        int j = i - total1;
        int d = j / CINP, c = j % CINP;
        float v = 0.0f;
        if (c < CIN && d < COUT) v = dw[(size_t)c * COUT + d];
        FD[j] = bf16e(v);
    }
    if (i < COUT) B[i] = cb[i] + (HAS_SELF ? db[i] : 0.0f);
}

// ---------------------------------------------------------------------------
// fused CConv, all-MFMA, W64-persistent, merged-mt phases (3 barriers per cc):
//   phase0: geometry writes dense W64[pt][64 taps][48 k] directly (write-once)
//   per cc: stage featsT once -> bar -> step1 all 4 mt (8 MFMA/wave, full A2)
//           -> bar -> step2 all 32 K-steps -> bar
//   self/dense branch: relu(self feats) MFMA with FD
// NOTE: MFMA is wave-cooperative — never branch around it with a
//       lane-divergent condition; zero the fragments instead (round-8 bug).
// OUT_MODE: 0 = X-slice, 1 = plain, 2 = +resid, 3 = final pos/vel
// ---------------------------------------------------------------------------
template <int CIN, int COUT, int HAS_SELF, int RELU_IN, int OUT_MODE>
__global__ void __launch_bounds__(512, 4) pn_cconv(
    const float* __restrict__ qpos, const float* __restrict__ ppos,
    const float* __restrict__ feats, const int* __restrict__ nbr,
    const unsigned short* __restrict__ F2t, const unsigned short* __restrict__ FD,
    const float* __restrict__ bias,
    const float* __restrict__ resid, float* __restrict__ outp,
    const float* __restrict__ pos0, int out_stride, int out_off)
{
    constexpr int CINP   = ((CIN + 15) / 16) * 16;
    constexpr int NCC    = CINP / 16;
    constexpr int DPAD   = ((COUT + 15) / 16) * 16;
    constexpr int NT     = DPAD / 16;
    constexpr int SPLITK = 8 / NT;
    constexpr int SPC2   = 32 / SPLITK;   // K-steps per wave in step2 (exact)
    constexpr int WST    = 48;            // row stride (bf16), 96B, 16B-aligned
    constexpr int A2ST   = 1032;          // A2 row stride (2064B, 16B-aligned)

    __shared__ int      sI[TM * KN];
    __shared__ int      sKN[TM];
    __shared__ __align__(16) unsigned short sW [TM * 64 * WST];   // 49152B, persistent
    __shared__ __align__(16) unsigned short sFT[TM * 16 * WST];   // 12288B (aliased late)
    __shared__ __align__(16) unsigned short sA2[TM * A2ST];       // 16512B

    float*          sEpi = (float*)sFT;            // 8192B, used after sFT dead
    unsigned short* sA3  = sFT + 4096;             // self staging, after sFT dead

    const int tid  = threadIdx.x;
    const int w    = tid >> 6;
    const int lane = tid & 63;
    const int n16  = lane & 15;
    const int kg   = lane >> 4;
    const int pt0  = blockIdx.x * TM;
    const int dt   = w % NT;
    const int kh   = w / NT;

    if (tid < TM) sKN[tid] = KN;
    // zero W64 once
    {
        uint4 z4 = make_uint4(0, 0, 0, 0);
        for (int i = tid; i < TM * 64 * WST / 8; i += 512) ((uint4*)sW)[i] = z4;
    }
    __syncthreads();

    // phase 0: geometry -> scatter into persistent W64 (write-once, no atomics)
    for (int e = tid; e < TM * KN; e += 512) {
        int lp = e / KN, k = e - lp * KN;
        int q  = pt0 + lp;
        int id = nbr[q * KN + k];
        if (id >= 0) {
            sI[e] = id;
            float rx = (ppos[id * 3 + 0] - qpos[q * 3 + 0]) * (1.0f / 0.1125f);
            float ry = (ppos[id * 3 + 1] - qpos[q * 3 + 1]) * (1.0f / 0.1125f);
            float rz = (ppos[id * 3 + 2] - qpos[q * 3 + 2]) * (1.0f / 0.1125f);
            unsigned g[8];
            pn_geom(rx, ry, rz, g);
#pragma unroll
            for (int j = 0; j < 8; ++j)
                sW[(lp * 64 + (int)(g[j] >> 16)) * WST + k] = (unsigned short)(g[j] & 0xffffu);
        } else {
            atomicMin(&sKN[lp], k);
        }
    }

    f32x4 acc = {0.0f, 0.0f, 0.0f, 0.0f};
    __syncthreads();

    for (int cc = 0; cc < NCC; ++cc) {
        const int cb0 = cc * 16;

        // stage transposed features ONCE per cc: sFT[pt][c][k]
        for (int e = tid; e < TM * KN; e += 512) {
            int pt = e / KN, k = e - pt * KN;
            unsigned short vals[16];
            if (k < sKN[pt]) {
                int id = sI[e];
                if constexpr (CIN % 16 == 0) {
                    const float4* s4 = (const float4*)(feats + (size_t)id * CIN + cb0);
#pragma unroll
                    for (int v4 = 0; v4 < 4; ++v4) {
                        float4 f = s4[v4];
                        if (RELU_IN) { f.x=fmaxf(f.x,0.f); f.y=fmaxf(f.y,0.f); f.z=fmaxf(f.z,0.f); f.w=fmaxf(f.w,0.f); }
                        vals[v4*4+0] = bf16e(f.x); vals[v4*4+1] = bf16e(f.y);
                        vals[v4*4+2] = bf16e(f.z); vals[v4*4+3] = bf16e(f.w);
                    }
                } else {
#pragma unroll
                    for (int c = 0; c < 16; ++c) {
                        float f = (cb0 + c < CIN) ? feats[(size_t)id * CIN + cb0 + c] : 0.0f;
                        if (RELU_IN) f = fmaxf(f, 0.0f);
                        vals[c] = bf16e(f);
                    }
                }
            } else {
#pragma unroll
                for (int c = 0; c < 16; ++c) vals[c] = 0;
            }
#pragma unroll
            for (int c = 0; c < 16; ++c) sFT[(pt * 16 + c) * WST + k] = vals[c];
        }
        __syncthreads();

        // step1 merged over mt: A2[pt][tap*16+c] for all 64 taps; wave w -> pt w
        // MFMA issued unconditionally; invalid K-lanes feed zero fragments.
        {
            const short8 z8 = {0,0,0,0,0,0,0,0};
            short8 bv[2];
#pragma unroll
            for (int s = 0; s < 2; ++s) {
                int kidx = s * 32 + kg * 8;
                bv[s] = z8;
                if (kidx < KN)
                    bv[s] = *(const short8*)(sFT + (w * 16 + n16) * WST + kidx);
            }
#pragma unroll
            for (int mt = 0; mt < 4; ++mt) {
                f32x4 a1 = {0.0f, 0.0f, 0.0f, 0.0f};
#pragma unroll
                for (int s = 0; s < 2; ++s) {
                    int kidx = s * 32 + kg * 8;
                    short8 av = z8;
                    if (kidx < KN)
                        av = *(const short8*)(sW + (w * 64 + mt * 16 + n16) * WST + kidx);
                    a1 = __builtin_amdgcn_mfma_f32_16x16x32_bf16(av, bv[s], a1, 0, 0, 0);
                }
#pragma unroll
                for (int r = 0; r < 4; ++r)
                    sA2[w * A2ST + (mt * 16 + kg * 4 + r) * 16 + n16] = bf16e(a1[r]);
            }
        }
        __syncthreads();

        // step2: acc += A2(TM pts x 1024) * F2t(1024 x DPAD); wave (dt,kh)
        {
            const unsigned short* gB = F2t + ((size_t)((cc * NT + dt) * 16 + n16)) * 1024;
            const int s0 = kh * SPC2;
            const short8 z8 = {0,0,0,0,0,0,0,0};
#pragma unroll 4
            for (int s2 = 0; s2 < SPC2; ++s2) {
                int k2 = (s0 + s2) * 32 + kg * 8;
                short8 av = (n16 < TM) ? *(const short8*)(sA2 + n16 * A2ST + k2) : z8;
                short8 bv = *(const short8*)(gB + k2);
                acc = __builtin_amdgcn_mfma_f32_16x16x32_bf16(av, bv, acc, 0, 0, 0);
            }
        }
        __syncthreads();
    }

    // self/dense branch: acc += relu(self feats) x FD   (sA3 aliases dead sFT)
    if constexpr (HAS_SELF) {
        constexpr int NP = NCC / 2;
        for (int ccp = 0; ccp < NP; ++ccp) {
            if (tid < TM * 32) {
                int pt = tid / 32, c = tid & 31;
                int cin = ccp * 32 + c;
                float f = (cin < CIN) ? feats[(size_t)(pt0 + pt) * CIN + cin] : 0.0f;
                if (RELU_IN) f = fmaxf(f, 0.0f);
                sA3[pt * 40 + c] = bf16e(f);
            }
            __syncthreads();
            if (ccp % SPLITK == kh) {    // wave-uniform condition: safe around MFMA
                const short8 z8 = {0,0,0,0,0,0,0,0};
                short8 av = (n16 < TM) ? *(const short8*)(sA3 + n16 * 40 + kg * 8) : z8;
                short8 bv = *(const short8*)(FD + (size_t)(dt * 16 + n16) * CINP + ccp * 32 + kg * 8);
                acc = __builtin_amdgcn_mfma_f32_16x16x32_bf16(av, bv, acc, 0, 0, 0);
            }
            __syncthreads();
        }
    }

    // epilogue: split-K combine + bias + output modes (sEpi aliases dead sFT)
#pragma unroll
    for (int r = 0; r < 4; ++r) sEpi[(w * 64 + lane) * 4 + r] = acc[r];
    __syncthreads();

    if (w < NT) {
        float sum[4];
#pragma unroll
        for (int r = 0; r < 4; ++r) {
            float s = 0.0f;
#pragma unroll
            for (int k = 0; k < SPLITK; ++k)
                s += sEpi[((k * NT + w) * 64 + lane) * 4 + r];
            sum[r] = s;
        }
        int d = w * 16 + n16;
        if (d < COUT) {
            float b = bias[d];
#pragma unroll
            for (int r = 0; r < 4; ++r) {
                int pt = kg * 4 + r;
                if (pt < TM) {
                    int q = pt0 + pt;
                    float y = sum[r] + b;
                    if constexpr (OUT_MODE == 0) {
                        outp[q * out_stride + out_off + d] = y;
                    } else if constexpr (OUT_MODE == 1) {
                        outp[q * COUT + d] = y;
                    } else if constexpr (OUT_MODE == 2) {
                        outp[q * COUT + d] = y + resid[q * COUT + d];
                    } else {
                        float corr = y * (1.0f / 128.0f);
                        float pn   = qpos[q * 3 + d];
                        float pc   = pn + corr;
                        outp[q * 3 + d]          = pc;
                        outp[NF * 3 + q * 3 + d] = (pc - pos0[q * 3 + d]) * (1.0f / 0.02f);
                    }
                }
            }
        }
    }
}

// ---------------------------------------------------------------------------
// host launcher
// ---------------------------------------------------------------------------
extern "C" void kernel_launch(void* const* d_in, const int* in_sizes, int n_in,
                              void* d_out, int out_size, void* d_ws, size_t ws_size,
                              hipStream_t stream)
{
    (void)in_sizes; (void)n_in; (void)out_size; (void)ws_size;

    const float* pos       = (const float*)d_in[0];
    const float* vel       = (const float*)d_in[1];
    const float* box       = (const float*)d_in[2];
    const float* box_feats = (const float*)d_in[3];
    const int*   nbrf      = (const int*)d_in[4];
    const int*   nbrb      = (const int*)d_in[5];
    const float* cf0_w = (const float*)d_in[6];
    const float* cf0_b = (const float*)d_in[7];
    const float* co0_w = (const float*)d_in[8];
    const float* co0_b = (const float*)d_in[9];
    const float* d0_w  = (const float*)d_in[10];
    const float* d0_b  = (const float*)d_in[11];
    const float* c1_w  = (const float*)d_in[12];
    const float* c1_b  = (const float*)d_in[13];
    const float* d1_w  = (const float*)d_in[14];
    const float* d1_b  = (const float*)d_in[15];
    const float* c2_w  = (const float*)d_in[16];
    const float* c2_b  = (const float*)d_in[17];
    const float* d2_w  = (const float*)d_in[18];
    const float* d2_b  = (const float*)d_in[19];
    const float* c3_w  = (const float*)d_in[20];
    const float* c3_b  = (const float*)d_in[21];
    const float* d3_w  = (const float*)d_in[22];
    const float* d3_b  = (const float*)d_in[23];

    char* ws = (char*)d_ws;
    float*          POSNEW = (float*)(ws + 0);        // 98304
    float*          FEATS0 = (float*)(ws + 98304);    // 131072
    float*          X      = (float*)(ws + 229376);   // 8192*96*4 = 3145728
    float*          X1     = (float*)(ws + 3375104);  // 2097152
    float*          X2     = (float*)(ws + 5472256);  // 2097152
    unsigned short* F2T1   = (unsigned short*)(ws + 7569408); // 786432
    unsigned short* F2T2   = (unsigned short*)(ws + 8355840); // 524288
    unsigned short* F2T3   = (unsigned short*)(ws + 8880128); // 131072
    unsigned short* F2Tf   = (unsigned short*)(ws + 9011200); // 65536
    unsigned short* F2To   = (unsigned short*)(ws + 9076736); // 65536
    unsigned short* FD1    = (unsigned short*)(ws + 9142272); // 12288
    unsigned short* FD2    = (unsigned short*)(ws + 9154560); // 8192
    unsigned short* FD3    = (unsigned short*)(ws + 9162752); // 2048
    float*          B1     = (float*)(ws + 9164800);
    float*          B2     = (float*)(ws + 9165056);
    float*          B3     = (float*)(ws + 9165312);
    float*          Bf0    = (float*)(ws + 9165568);
    float*          Bo0    = (float*)(ws + 9165824);

    float* out_f = (float*)d_out;

    // packs: <CIN, COUT, HAS_SELF>; grid covers F2t + FD
    pn_pack<96, 64, 1><<<(6*4*16*1024 + 64*96 + 255) / 256, 256, 0, stream>>>(c1_w, d1_w, c1_b, d1_b, F2T1, FD1, B1);
    pn_pack<64, 64, 1><<<(4*4*16*1024 + 64*64 + 255) / 256, 256, 0, stream>>>(c2_w, d2_w, c2_b, d2_b, F2T2, FD2, B2);
    pn_pack<64, 3, 1><<<(4*1*16*1024 + 16*64 + 255) / 256, 256, 0, stream>>>(c3_w, d3_w, c3_b, d3_b, F2T3, FD3, B3);
    pn_pack<4, 32, 0><<<(1*2*16*1024 + 255) / 256, 256, 0, stream>>>(cf0_w, nullptr, cf0_b, nullptr, F2Tf, nullptr, Bf0);
    pn_pack<3, 32, 0><<<(1*2*16*1024 + 255) / 256, 256, 0, stream>>>(co0_w, nullptr, co0_b, nullptr, F2To, nullptr, Bo0);

    pn_prep<<<(NF + 255) / 256, 256, 0, stream>>>(pos, vel, nbrf, d0_w, d0_b,
                                                  POSNEW, FEATS0, X, out_f + NF * 6);

    // convs: <CIN, COUT, HAS_SELF, RELU_IN, OUT_MODE>, grid NF/8, 512 thr
    pn_cconv<4, 32, 0, 0, 0><<<NF / TM, 512, 0, stream>>>(
        POSNEW, POSNEW, FEATS0, nbrf, F2Tf, nullptr, Bf0, nullptr, X, nullptr, 96, 32);
    pn_cconv<3, 32, 0, 0, 0><<<NF / TM, 512, 0, stream>>>(
        POSNEW, box, box_feats, nbrb, F2To, nullptr, Bo0, nullptr, X, nullptr, 96, 0);
    pn_cconv<96, 64, 1, 1, 1><<<NF / TM, 512, 0, stream>>>(
        POSNEW, POSNEW, X, nbrf, F2T1, FD1, B1, nullptr, X1, nullptr, 0, 0);
    pn_cconv<64, 64, 1, 1, 2><<<NF / TM, 512, 0, stream>>>(
        POSNEW, POSNEW, X1, nbrf, F2T2, FD2, B2, X1, X2, nullptr, 0, 0);
    pn_cconv<64, 3, 1, 1, 3><<<NF / TM, 512, 0, stream>>>(
        POSNEW, POSNEW, X2, nbrf, F2T3, FD3, B3, nullptr, out_f, pos, 0, 0);
}